// Round 11
// baseline (35.495 us; speedup 1.0000x reference)
//
#include <hip/hip_runtime.h>
#include <math.h>

constexpr int BATCH = 4096;
constexpr int DIM   = 2048;
constexpr int REPS  = 8;
constexpr float INV2PI = 0.15915494309189535f;  // 1/(2*pi)

constexpr int TPB   = 256;
constexpr int GRIDX = DIM / TPB;       // 8
constexpr int GRIDY = 256;             // 2048 blocks = 8 blocks/CU (R2/R9-proven TLP)
constexpr int BPB   = BATCH / GRIDY;   // 16 rows per block
constexpr int ILP   = 2;
constexpr int NCH   = BPB / ILP;       // 8 chunks

// R6-proven polynomial sincos of 2*pi*f (f revolutions), |err| ~1e-4, 12 VALU ops.
__device__ __forceinline__ void poly_sincos(float f, float& s, float& c) {
    const float m = __builtin_rintf(f);
    const float r = f - m;                // |r| <= 0.5
    const float u = r * r;
    float p = fmaf(32.7680000f, u, -74.4701952f);   // sin deg-9 odd
    p = fmaf(p, u, 81.3660160f);
    p = fmaf(p, u, -41.3311104f);
    p = fmaf(p, u, 6.2830536f);
    s = p * r;
    float q = fmaf(45.6130560f, u, -82.3881728f);   // cos deg-8 even
    q = fmaf(q, u, 64.6713088f);
    q = fmaf(q, u, -19.7309120f);
    c = fmaf(q, u, 0.9999527f);
}

__global__ __launch_bounds__(TPB, 4)
void daruan_kernel(const float* __restrict__ x,       // (BATCH, DIM)
                   const float* __restrict__ theta,   // (DIM, 9, 2)
                   const float* __restrict__ paw,     // (DIM, 8)
                   const float* __restrict__ pab,     // (DIM, 8)
                   const float* __restrict__ postw,   // (DIM)
                   const float* __restrict__ postb,   // (DIM)
                   float* __restrict__ out)           // (BATCH, DIM)
{
    const int d = blockIdx.x * TPB + threadIdx.x;   // lane-per-d: coalesced

    // ---- per-d preamble (R2-proven folding): RZ(t0[0])+RY(t1[0]) -> initial
    // Bloch state; RZ(t0[r+1]) (incl. final) -> rep r's encoding bias.
    const float* th = theta + (size_t)d * 18;
    const float t00 = th[0] * INV2PI;
    const float X0  = __builtin_amdgcn_cosf(t00);
    const float Y0  = __builtin_amdgcn_sinf(t00);
    const float t10 = th[1] * INV2PI;
    const float Xi  = X0 * __builtin_amdgcn_cosf(t10);
    const float Yi  = Y0;
    const float Zi  = -X0 * __builtin_amdgcn_sinf(t10);

    float cy[REPS], sy[REPS], wr[REPS], br[REPS];
#pragma unroll
    for (int k = 0; k < REPS; ++k) {
        const float t1 = th[2 * k + 3] * INV2PI;        // theta1[k+1]
        cy[k] = __builtin_amdgcn_cosf(t1);
        sy[k] = __builtin_amdgcn_sinf(t1);
        wr[k] = paw[(size_t)d * REPS + k] * INV2PI;
        br[k] = (pab[(size_t)d * REPS + k] + th[2 * (k + 1)]) * INV2PI;
    }
    const float pw = postw[d];
    const float pb = postb[d];

    const int bbase = blockIdx.y * BPB;
    const float* xp = x + (size_t)bbase * DIM + d;
    float* op = out + (size_t)bbase * DIM + d;

    auto do_elem = [&](float xv) -> float {
        // phase 1: even reps {0,2,4,6} on the HW trans pipe — issued first so
        // their latency hides under the poly VALU work below
        float seh[4], ceh[4];
#pragma unroll
        for (int j = 0; j < 4; ++j) {
            const float e = fmaf(wr[2 * j], xv, br[2 * j]);
            seh[j] = __builtin_amdgcn_sinf(e);
            ceh[j] = __builtin_amdgcn_cosf(e);
        }
        // phase 2: odd reps {1,3,5,7} on the VALU pipe (concurrent resource)
        float sep[4], cep[4];
#pragma unroll
        for (int j = 0; j < 4; ++j)
            poly_sincos(fmaf(wr[2 * j + 1], xv, br[2 * j + 1]), sep[j], cep[j]);
        // phase 3: pure-fma state chain
        float X = fmaf(Xi, ceh[0], -Yi * seh[0]);
        float Y = fmaf(Xi, seh[0],  Yi * ceh[0]);
        float Z = Zi;
#pragma unroll
        for (int r = 1; r < REPS; ++r) {
            const float se = (r & 1) ? sep[r >> 1] : seh[r >> 1];  // compile-time
            const float ce = (r & 1) ? cep[r >> 1] : ceh[r >> 1];
            const float Xb = fmaf(X, cy[r - 1],  Z * sy[r - 1]);
            const float Zb = fmaf(Z, cy[r - 1], -X * sy[r - 1]);
            X = fmaf(Xb, ce, -Y * se);
            if (r < REPS - 1)                       // Y dead after last rep
                Y = fmaf(Xb, se, Y * ce);
            Z = Zb;
        }
        return fmaf(Z, cy[REPS - 1], -X * sy[REPS - 1]);   // final RY
    };

    float xv[ILP];
#pragma unroll
    for (int i = 0; i < ILP; ++i) xv[i] = xp[(size_t)i * DIM];

#pragma unroll 1
    for (int cc = 0; cc < NCH - 1; ++cc) {
        float xn[ILP];
#pragma unroll
        for (int i = 0; i < ILP; ++i)     // prefetch next chunk's x
            xn[i] = xp[(size_t)((cc + 1) * ILP + i) * DIM];
#pragma unroll
        for (int i = 0; i < ILP; ++i)
            op[(size_t)(cc * ILP + i) * DIM] = fmaf(do_elem(xv[i]), pw, pb);
#pragma unroll
        for (int i = 0; i < ILP; ++i) xv[i] = xn[i];
    }
#pragma unroll
    for (int i = 0; i < ILP; ++i)
        op[(size_t)((NCH - 1) * ILP + i) * DIM] = fmaf(do_elem(xv[i]), pw, pb);
}

extern "C" void kernel_launch(void* const* d_in, const int* in_sizes, int n_in,
                              void* d_out, int out_size, void* d_ws, size_t ws_size,
                              hipStream_t stream) {
    const float* x     = (const float*)d_in[0];
    const float* theta = (const float*)d_in[1];
    const float* paw   = (const float*)d_in[2];
    const float* pab   = (const float*)d_in[3];
    const float* postw = (const float*)d_in[4];
    const float* postb = (const float*)d_in[5];
    float* out = (float*)d_out;

    daruan_kernel<<<dim3(GRIDX, GRIDY), dim3(TPB), 0, stream>>>(
        x, theta, paw, pab, postw, postb, out);
}

// Round 12
// 32.506 us; speedup vs baseline: 1.0920x; 1.0920x over previous
//
#include <hip/hip_runtime.h>
#include <math.h>

constexpr int BATCH = 4096;
constexpr int DIM   = 2048;
constexpr int REPS  = 8;
constexpr float INV2PI = 0.15915494309189535f;  // 1/(2*pi)

constexpr int TPB   = 256;
constexpr int GRIDX = DIM / TPB;       // 8
constexpr int GRIDY = 256;             // 2048 blocks = 8 blocks/CU
constexpr int BPB   = BATCH / GRIDY;   // 16 rows per block

// Force a value to live in a VGPR: read-write asm constraint makes it opaque
// (cannot be rematerialized or folded; the allocator must carry the register).
#define PIN(v) asm volatile("" : "+v"(v))

__global__ __launch_bounds__(TPB, 4)
void daruan_kernel(const float* __restrict__ x,       // (BATCH, DIM)
                   const float* __restrict__ theta,   // (DIM, 9, 2)
                   const float* __restrict__ paw,     // (DIM, 8)
                   const float* __restrict__ pab,     // (DIM, 8)
                   const float* __restrict__ postw,   // (DIM)
                   const float* __restrict__ postb,   // (DIM)
                   float* __restrict__ out)           // (BATCH, DIM)
{
    const int d = blockIdx.x * TPB + threadIdx.x;   // lane-per-d: coalesced

    // ---- per-d preamble (R2-proven folding): RZ(t0[0])+RY(t1[0]) -> initial
    // Bloch state; RZ(t0[r+1]) (incl. final) -> rep r's encoding bias.
    const float* th = theta + (size_t)d * 18;
    const float t00 = th[0] * INV2PI;
    const float X0  = __builtin_amdgcn_cosf(t00);
    const float Y0  = __builtin_amdgcn_sinf(t00);
    const float t10 = th[1] * INV2PI;
    float Xi  = X0 * __builtin_amdgcn_cosf(t10);
    float Yi  = Y0;
    float Zi  = -X0 * __builtin_amdgcn_sinf(t10);

    float cy[REPS], sy[REPS], wr[REPS], br[REPS];
#pragma unroll
    for (int k = 0; k < REPS; ++k) {
        const float t1 = th[2 * k + 3] * INV2PI;        // theta1[k+1]
        cy[k] = __builtin_amdgcn_cosf(t1);
        sy[k] = __builtin_amdgcn_sinf(t1);
        wr[k] = paw[(size_t)d * REPS + k] * INV2PI;
        br[k] = (pab[(size_t)d * REPS + k] + th[2 * (k + 1)]) * INV2PI;
    }
    float pw = postw[d];
    float pb = postb[d];

    // ---- pin all 37 per-d constants into VGPRs: no remat, no reload ----
#pragma unroll
    for (int k = 0; k < REPS; ++k) { PIN(cy[k]); PIN(sy[k]); PIN(wr[k]); PIN(br[k]); }
    PIN(Xi); PIN(Yi); PIN(Zi); PIN(pw); PIN(pb);

    const int bbase = blockIdx.y * BPB;
    const float* xp = x + (size_t)bbase * DIM + d;
    float* op = out + (size_t)bbase * DIM + d;

    auto do_elem = [&](float xv) -> float {
        // all 16 trans issued up front (angles independent of state)
        float se[REPS], ce[REPS];
#pragma unroll
        for (int r = 0; r < REPS; ++r) {
            const float e = fmaf(wr[r], xv, br[r]);
            se[r] = __builtin_amdgcn_sinf(e);
            ce[r] = __builtin_amdgcn_cosf(e);
        }
        // pure-fma state chain
        float X = fmaf(Xi, ce[0], -Yi * se[0]);
        float Y = fmaf(Xi, se[0],  Yi * ce[0]);
        float Z = Zi;
#pragma unroll
        for (int r = 1; r < REPS; ++r) {
            const float Xb = fmaf(X, cy[r - 1],  Z * sy[r - 1]);
            const float Zb = fmaf(Z, cy[r - 1], -X * sy[r - 1]);
            X = fmaf(Xb, ce[r], -Y * se[r]);
            if (r < REPS - 1)                      // Y dead after last rep
                Y = fmaf(Xb, se[r], Y * ce[r]);
            Z = Zb;
        }
        return fmaf(Z, cy[REPS - 1], -X * sy[REPS - 1]);   // final RY
    };

    float xv = xp[0];
#pragma unroll 1
    for (int c = 0; c < BPB; ++c) {
        // branch-free next-x prefetch (wraps on final iter; value discarded)
        const float xn = xp[(size_t)((c + 1) & (BPB - 1)) * DIM];
        op[(size_t)c * DIM] = fmaf(do_elem(xv), pw, pb);
        xv = xn;
    }
}

extern "C" void kernel_launch(void* const* d_in, const int* in_sizes, int n_in,
                              void* d_out, int out_size, void* d_ws, size_t ws_size,
                              hipStream_t stream) {
    const float* x     = (const float*)d_in[0];
    const float* theta = (const float*)d_in[1];
    const float* paw   = (const float*)d_in[2];
    const float* pab   = (const float*)d_in[3];
    const float* postw = (const float*)d_in[4];
    const float* postb = (const float*)d_in[5];
    float* out = (float*)d_out;

    daruan_kernel<<<dim3(GRIDX, GRIDY), dim3(TPB), 0, stream>>>(
        x, theta, paw, pab, postw, postb, out);
}